// Round 1
// 1469.589 us; speedup vs baseline: 1.0958x; 1.0958x over previous
//
#include <hip/hip_runtime.h>

typedef unsigned short u16;
typedef __attribute__((ext_vector_type(4))) float f32x4;
typedef __attribute__((ext_vector_type(8))) __bf16 bf16x8;

__device__ __forceinline__ u16 f2bf(float f) {
  unsigned u = __float_as_uint(f);
  u += 0x7fffu + ((u >> 16) & 1u);   // round-to-nearest-even
  return (u16)(u >> 16);
}
__device__ __forceinline__ float bf2f(u16 h) {
  return __uint_as_float((unsigned)h << 16);
}

__device__ __forceinline__ void g2l16(const void* g, void* l) {
  __builtin_amdgcn_global_load_lds(
      (const __attribute__((address_space(1))) void*)g,
      (__attribute__((address_space(3))) void*)l, 16, 0, 0);
}

#define BAR() __builtin_amdgcn_s_barrier()
#define SCHED0() __builtin_amdgcn_sched_barrier(0)
#define LGKM0()                                         \
  do {                                                  \
    asm volatile("s_waitcnt lgkmcnt(0)" ::: "memory");  \
    SCHED0();                                           \
  } while (0)
#define VMCNT(n)                                          \
  do {                                                    \
    asm volatile("s_waitcnt vmcnt(" #n ")" ::: "memory"); \
  } while (0)

// ---------------------------------------------------------------------------
// 256x256 8-phase GEMM (T1+T2+T3+T4+T5), C = A @ B with Bt = B^T row-major.
// A: [M][SPLIT*K] bf16, Bt: [N][SPLIT*K] bf16. Per-split K is the template K.
// 8 waves (2M x 4N), BK=64, double-buffered 128 KiB LDS, per-phase:
//   {ds_read quadrant frags | stage 1 half-tile | bar | lgkm0 | 16 MFMA | bar}
// vmcnt(4) only at phases 4/8 (2 half-tiles stay in flight across barriers).
// MODE 1: Cb = bf16(silu(acc + bias[col])). MODE 2: Cb = bf16(acc).
// SPLIT=2: split-K, split s writes Cb + s*M*N (partials summed by consumer).
// ---------------------------------------------------------------------------
template <int MODE, int SPLIT, int NBN, int K>
__global__ __launch_bounds__(512, 2)
void gemm256(const u16* __restrict__ A, const u16* __restrict__ Bt,
             u16* __restrict__ Cb, const float* __restrict__ bias)
{
  constexpr int N = NBN * 256;
  constexpr int LDA = SPLIT * K;       // full-K row stride
  constexpr int LDB = SPLIT * K;
  constexpr int NT = K / 64;           // K-tiles per split
  constexpr int NITER = NT / 2;        // 2 K-tiles per 8-phase iteration
  static_assert(NITER >= 2, "pipeline needs >= 4 K-tiles");

  // units: 0 = A-h0 (rows {0..63,128..191}), 1 = A-h1 (rows {64..127,192..255})
  //        2 = B-h0 (cols with bit5==0),     3 = B-h1 (cols with bit5==1)
  __shared__ __align__(16) u16 lds[2][4][8192];   // 128 KiB

  const int tid = threadIdx.x;
  const int lane = tid & 63;
  const int wave = tid >> 6;
  const int wm = wave >> 2;            // 2 row groups (128 rows each)
  const int wn = wave & 3;             // 4 col groups (64 cols each)
  const int lm = lane & 15;
  const int lq = lane >> 4;
  const int swz = lm & 7;
  const int j0 = lq ^ swz;             // de-swizzled k-chunk, k-half 0
  const int j1 = (4 + lq) ^ swz;       // k-half 1

  // XCD-bijective block swizzle (nwg % 8 == 0 for all call sites)
  const int nwg = (int)gridDim.x;
  const int bid = (int)blockIdx.x;
  const int id = (bid & 7) * (nwg >> 3) + (bid >> 3);
  const int bps = (SPLIT == 1) ? nwg : (nwg / SPLIT);
  const int sp = (SPLIT == 1) ? 0 : (id / bps);
  const int rres = (SPLIT == 1) ? id : (id % bps);
  const int bm = rres / NBN;
  const int bn = rres % NBN;
  const long long row0 = (long long)bm * 256;
  const long long col0 = (long long)bn * 256;
  const int M = (bps / NBN) * 256;
  const long long spK = (long long)sp * K;

  // k-invariant per-thread staging source pointers (it=1 adds uniform 128*LD)
  const int rh = tid >> 3;             // 0..63
  const int jj = tid & 7;
  const u16* gA[2];
  const u16* gB[2];
  {
    const int jsA = jj ^ (rh & 7);
#pragma unroll
    for (int h = 0; h < 2; ++h)
      gA[h] = A + (row0 + h * 64 + rh) * LDA + spK + jsA * 8;
    const int st = rh >> 5, c32 = rh & 31;
    const int jsB = jj ^ (c32 & 7);
#pragma unroll
    for (int h = 0; h < 2; ++h)
      gB[h] = Bt + (col0 + st * 64 + h * 32 + c32) * LDB + spK + jsB * 8;
  }
  const int ldsBase0 = wave * 64 * 8;  // wave-uniform dest (it=0); it=1: +4096

  auto stageA = [&](int buf, int h, int tk) {
    const u16* s = gA[h] + tk * 64;
    g2l16(s, &lds[buf][h][ldsBase0]);
    g2l16(s + 128 * LDA, &lds[buf][h][ldsBase0 + 4096]);
  };
  auto stageB = [&](int buf, int h, int tk) {
    const u16* s = gB[h] + tk * 64;
    g2l16(s, &lds[buf][2 + h][ldsBase0]);
    g2l16(s + 128 * LDB, &lds[buf][2 + h][ldsBase0 + 4096]);
  };

  bf16x8 fa[4][2], fbA[2][2], fbB[2][2];
  auto loadFA = [&](int buf, int h) {
    const u16* u = &lds[buf][h][0];
#pragma unroll
    for (int t = 0; t < 4; ++t) {
      const u16* rp = u + (wm * 64 + t * 16 + lm) * 64;
      fa[t][0] = *(const bf16x8*)(rp + j0 * 8);
      fa[t][1] = *(const bf16x8*)(rp + j1 * 8);
    }
  };
  auto loadFB = [&](bf16x8 (*dst)[2], int buf, int h) {
    const u16* u = &lds[buf][2 + h][0];
#pragma unroll
    for (int c = 0; c < 2; ++c) {
      const u16* rp = u + (wn * 32 + c * 16 + lm) * 64;
      dst[c][0] = *(const bf16x8*)(rp + j0 * 8);
      dst[c][1] = *(const bf16x8*)(rp + j1 * 8);
    }
  };

  f32x4 acc[8][4] = {};

#define QMFMA(RB, CB, FB)                                                   \
  do {                                                                      \
    __builtin_amdgcn_s_setprio(1);                                          \
    _Pragma("unroll") for (int r_ = 0; r_ < 4; ++r_) {                      \
      _Pragma("unroll") for (int c_ = 0; c_ < 2; ++c_) {                    \
        acc[RB + r_][CB + c_] = __builtin_amdgcn_mfma_f32_16x16x32_bf16(    \
            fa[r_][0], FB[c_][0], acc[RB + r_][CB + c_], 0, 0, 0);          \
        acc[RB + r_][CB + c_] = __builtin_amdgcn_mfma_f32_16x16x32_bf16(    \
            fa[r_][1], FB[c_][1], acc[RB + r_][CB + c_], 0, 0, 0);          \
      }                                                                     \
    }                                                                       \
    __builtin_amdgcn_s_setprio(0);                                          \
  } while (0)

  // prologue: tile0 fully + tile1's A-h0,B-h1; oldest-8 = tile0 -> vmcnt(4)
  stageA(0, 0, 0); stageA(0, 1, 0); stageB(0, 0, 0); stageB(0, 1, 0);
  stageA(1, 0, 1); stageB(1, 1, 1);
  VMCNT(4);
  BAR();

#pragma unroll 1
  for (int i = 0; i < NITER - 1; ++i) {
    const int tk = 2 * i;
    // P1: Q(top,left) of tile tk (buf0)
    loadFA(0, 0); loadFB(fbA, 0, 0);
    stageA(1, 1, tk + 1);
    BAR(); LGKM0();
    QMFMA(0, 0, fbA);
    BAR();
    // P2: Q(top,right)
    loadFB(fbB, 0, 1);
    stageB(1, 0, tk + 1);
    BAR(); LGKM0();
    QMFMA(0, 2, fbB);
    BAR();
    // P3: Q(bottom,right)
    loadFA(0, 1);
    stageA(0, 0, tk + 2);
    BAR(); LGKM0();
    QMFMA(4, 2, fbB);
    BAR();
    // P4: Q(bottom,left); counted vmcnt -> buf1 (tile tk+1) fully landed
    stageB(0, 1, tk + 2);
    VMCNT(4);
    BAR();
    QMFMA(4, 0, fbA);
    BAR();
    // P5..P8: tile tk+1 (buf1)
    loadFA(1, 0); loadFB(fbA, 1, 0);
    stageA(0, 1, tk + 2);
    BAR(); LGKM0();
    QMFMA(0, 0, fbA);
    BAR();
    loadFB(fbB, 1, 1);
    stageB(0, 0, tk + 2);
    BAR(); LGKM0();
    QMFMA(0, 2, fbB);
    BAR();
    loadFA(1, 1);
    stageA(1, 0, tk + 3);
    BAR(); LGKM0();
    QMFMA(4, 2, fbB);
    BAR();
    stageB(1, 1, tk + 3);
    VMCNT(4);
    BAR();
    QMFMA(4, 0, fbA);
    BAR();
  }
  {
    // tail iteration: finish staging tile NT-1, drain, no further prefetch
    const int tk = 2 * (NITER - 1);
    loadFA(0, 0); loadFB(fbA, 0, 0);
    stageA(1, 1, tk + 1);
    BAR(); LGKM0();
    QMFMA(0, 0, fbA);
    BAR();
    loadFB(fbB, 0, 1);
    stageB(1, 0, tk + 1);
    BAR(); LGKM0();
    QMFMA(0, 2, fbB);
    BAR();
    loadFA(0, 1);
    BAR(); LGKM0();
    QMFMA(4, 2, fbB);
    BAR();
    VMCNT(0);
    BAR();
    QMFMA(4, 0, fbA);
    BAR();
    loadFA(1, 0); loadFB(fbA, 1, 0);
    BAR(); LGKM0();
    QMFMA(0, 0, fbA);
    BAR();
    loadFB(fbB, 1, 1);
    BAR(); LGKM0();
    QMFMA(0, 2, fbB);
    BAR();
    loadFA(1, 1);
    BAR(); LGKM0();
    QMFMA(4, 2, fbB);
    BAR();
    QMFMA(4, 0, fbA);
  }
#undef QMFMA

  // epilogue: C/D layout col = lane&15, row = (lane>>4)*4 + reg (m89-verified)
  u16* Cout = Cb + (size_t)sp * ((size_t)M * N);
  float bcol[4];
  if (MODE == 1) {
#pragma unroll
    for (int cb = 0; cb < 4; ++cb)
      bcol[cb] = bias[col0 + wn * 64 + cb * 16 + lm];
  }
#pragma unroll
  for (int rb = 0; rb < 8; ++rb) {
    const long long grow = row0 + wm * 128 + rb * 16 + lq * 4;
#pragma unroll
    for (int cb = 0; cb < 4; ++cb) {
      const long long gcol = col0 + wn * 64 + cb * 16 + lm;
#pragma unroll
      for (int r = 0; r < 4; ++r) {
        long long idx = (grow + r) * N + gcol;
        float v = acc[rb][cb][r];
        if (MODE == 1) {
          float x = v + bcol[cb];
          Cout[idx] = f2bf(x / (1.f + __expf(-x)));
        } else {
          Cout[idx] = f2bf(v);
        }
      }
    }
  }
  (void)bias;
}

// ---------------------------------------------------------------------------
// Old 128x128 kernel: kept for E x E GEMMs, prologue (K=256) and weight prep.
// ---------------------------------------------------------------------------
template <int MODE, int N, int K>
__global__ __launch_bounds__(256)
void gemm_bt(const u16* __restrict__ A, const u16* __restrict__ Bt,
             float* __restrict__ Cf, u16* __restrict__ Cb,
             const float* __restrict__ bias)
{
  __shared__ u16 sA[128 * 64];
  __shared__ u16 sB[128 * 64];
  const int tid = threadIdx.x;
  const int lane = tid & 63;
  const int wave = tid >> 6;
  const int wm = wave >> 1;
  const int wn = wave & 1;
  const long long row0 = (long long)blockIdx.x * 128;
  const long long col0 = (long long)blockIdx.y * 128;
  const int lm = lane & 15;
  const int lq = lane >> 4;

  const u16* gA[4];
  const u16* gB[4];
#pragma unroll
  for (int it = 0; it < 4; ++it) {
    int c = it * 256 + tid;
    int r = c >> 3;
    int js = (c & 7) ^ (r & 7);
    gA[it] = A + (row0 + r) * K + js * 8;
    gB[it] = Bt + (col0 + r) * K + js * 8;
  }

  f32x4 acc[4][4] = {};

  for (int k0 = 0; k0 < K; k0 += 64) {
#pragma unroll
    for (int it = 0; it < 4; ++it) {
      int ub = (it * 256 + wave * 64) * 8;
      g2l16(gA[it] + k0, &sA[ub]);
      g2l16(gB[it] + k0, &sB[ub]);
    }
    __syncthreads();
#pragma unroll
    for (int s = 0; s < 2; ++s) {
      bf16x8 af[4], bfr[4];
#pragma unroll
      for (int t = 0; t < 4; ++t) {
        int ra = wm * 64 + t * 16 + lm;
        int ja = (s * 4 + lq) ^ (ra & 7);
        af[t] = *(const bf16x8*)&sA[ra * 64 + ja * 8];
        int rb = wn * 64 + t * 16 + lm;
        int jb = (s * 4 + lq) ^ (rb & 7);
        bfr[t] = *(const bf16x8*)&sB[rb * 64 + jb * 8];
      }
#pragma unroll
      for (int i = 0; i < 4; ++i)
#pragma unroll
        for (int j = 0; j < 4; ++j)
          acc[i][j] = __builtin_amdgcn_mfma_f32_16x16x32_bf16(af[i], bfr[j], acc[i][j], 0, 0, 0);
    }
    __syncthreads();
  }

  const int rb0 = lq * 4;
#pragma unroll
  for (int i = 0; i < 4; ++i) {
#pragma unroll
    for (int j = 0; j < 4; ++j) {
      long long grow = row0 + wm * 64 + i * 16 + rb0;
      long long gcol = col0 + wn * 64 + j * 16 + lm;
      float bcol = (MODE == 1) ? bias[gcol] : 0.f;
#pragma unroll
      for (int r = 0; r < 4; ++r) {
        long long idx = (grow + r) * N + gcol;
        float v = acc[i][j][r];
        if (MODE == 0) {
          Cf[idx] = v;
        } else if (MODE == 1) {
          float x = v + bcol;
          float sv = x / (1.f + __expf(-x));
          Cb[idx] = f2bf(sv);
        } else {
          Cb[idx] = f2bf(v);
        }
      }
    }
  }
}

// x = zc(bf16) + Y(bf16) + bvo ; z1 = LN(x)*g + b -> bf16. One wave per row.
__global__ __launch_bounds__(256)
void ln1_kernel(const u16* __restrict__ zc, const u16* __restrict__ Y,
                const float* __restrict__ bvo, const float* __restrict__ g,
                const float* __restrict__ b, u16* __restrict__ z1b)
{
  const int row = blockIdx.x * 4 + (threadIdx.x >> 6);
  const int lane = threadIdx.x & 63;
  const long long base = (long long)row * 1024;
  const ushort4* pz = (const ushort4*)(zc + base);
  const ushort4* py = (const ushort4*)(Y + base);
  const float4* pb = (const float4*)bvo;
  float4 x[4];
  float s = 0.f, s2 = 0.f;
#pragma unroll
  for (int i = 0; i < 4; ++i) {
    int idx = lane + 64 * i;
    ushort4 a = pz[idx]; ushort4 yu = py[idx]; float4 bv = pb[idx];
    float4 v;
    v.x = bf2f(a.x) + bf2f(yu.x) + bv.x; v.y = bf2f(a.y) + bf2f(yu.y) + bv.y;
    v.z = bf2f(a.z) + bf2f(yu.z) + bv.z; v.w = bf2f(a.w) + bf2f(yu.w) + bv.w;
    x[i] = v;
    s  += v.x + v.y + v.z + v.w;
    s2 += v.x * v.x + v.y * v.y + v.z * v.z + v.w * v.w;
  }
#pragma unroll
  for (int off = 32; off > 0; off >>= 1) {
    s  += __shfl_xor(s, off);
    s2 += __shfl_xor(s2, off);
  }
  const float mean = s * (1.0f / 1024.0f);
  const float var = s2 * (1.0f / 1024.0f) - mean * mean;
  const float rs = rsqrtf(var + 1e-5f);
  const float4* pg = (const float4*)g;
  const float4* pbb = (const float4*)b;
  ushort4* pob = (ushort4*)(z1b + base);
#pragma unroll
  for (int i = 0; i < 4; ++i) {
    int idx = lane + 64 * i;
    float4 gg = pg[idx], b2 = pbb[idx], v = x[i], o;
    o.x = (v.x - mean) * rs * gg.x + b2.x;
    o.y = (v.y - mean) * rs * gg.y + b2.y;
    o.z = (v.z - mean) * rs * gg.z + b2.z;
    o.w = (v.w - mean) * rs * gg.w + b2.w;
    pob[idx] = make_ushort4(f2bf(o.x), f2bf(o.y), f2bf(o.z), f2bf(o.w));
  }
}

// x = z1(bf16) + F(bf16) + F2(bf16, split-K partial) + b2c ; z = LN(x)*g + b ;
// last iter: zout(fp32) = z ; else zc = z + z_init -> bf16.
__global__ __launch_bounds__(256)
void ln2_kernel(const u16* __restrict__ z1, const u16* __restrict__ F,
                const u16* __restrict__ F2, const float* __restrict__ b2c,
                const float* __restrict__ g, const float* __restrict__ b,
                const float* __restrict__ zinit, float* __restrict__ zout,
                u16* __restrict__ zcb, int write_zc)
{
  const int row = blockIdx.x * 4 + (threadIdx.x >> 6);
  const int lane = threadIdx.x & 63;
  const long long base = (long long)row * 1024;
  const ushort4* pz = (const ushort4*)(z1 + base);
  const ushort4* pf = (const ushort4*)(F + base);
  const ushort4* pf2 = (const ushort4*)(F2 + base);
  const float4* pb = (const float4*)b2c;
  float4 x[4];
  float s = 0.f, s2 = 0.f;
#pragma unroll
  for (int i = 0; i < 4; ++i) {
    int idx = lane + 64 * i;
    ushort4 a = pz[idx]; ushort4 fu = pf[idx]; ushort4 f2u = pf2[idx];
    float4 bv = pb[idx];
    float4 v;
    v.x = bf2f(a.x) + bf2f(fu.x) + bf2f(f2u.x) + bv.x;
    v.y = bf2f(a.y) + bf2f(fu.y) + bf2f(f2u.y) + bv.y;
    v.z = bf2f(a.z) + bf2f(fu.z) + bf2f(f2u.z) + bv.z;
    v.w = bf2f(a.w) + bf2f(fu.w) + bf2f(f2u.w) + bv.w;
    x[i] = v;
    s  += v.x + v.y + v.z + v.w;
    s2 += v.x * v.x + v.y * v.y + v.z * v.z + v.w * v.w;
  }
#pragma unroll
  for (int off = 32; off > 0; off >>= 1) {
    s  += __shfl_xor(s, off);
    s2 += __shfl_xor(s2, off);
  }
  const float mean = s * (1.0f / 1024.0f);
  const float var = s2 * (1.0f / 1024.0f) - mean * mean;
  const float rs = rsqrtf(var + 1e-5f);
  const float4* pg = (const float4*)g;
  const float4* pbb = (const float4*)b;
  const float4* pzi = (const float4*)(zinit + base);
#pragma unroll
  for (int i = 0; i < 4; ++i) {
    int idx = lane + 64 * i;
    float4 gg = pg[idx], bb = pbb[idx], v = x[i], o;
    o.x = (v.x - mean) * rs * gg.x + bb.x;
    o.y = (v.y - mean) * rs * gg.y + bb.y;
    o.z = (v.z - mean) * rs * gg.z + bb.z;
    o.w = (v.w - mean) * rs * gg.w + bb.w;
    if (zout) ((float4*)(zout + base))[idx] = o;
    if (write_zc) {
      float4 zi = pzi[idx];
      ((ushort4*)(zcb + base))[idx] = make_ushort4(
          f2bf(o.x + zi.x), f2bf(o.y + zi.y), f2bf(o.z + zi.z), f2bf(o.w + zi.w));
    }
  }
}

// z = z_init + Yc(bf16) + ctrl_b + err @ err_W + err_b ; zc = z + z_init -> bf16
__global__ __launch_bounds__(256)
void prologue_fin(const float* __restrict__ zinit, const u16* __restrict__ Yc,
                  const float* __restrict__ ctrl_b, const float* __restrict__ err,
                  const float* __restrict__ err_W, const float* __restrict__ err_b,
                  u16* __restrict__ zcb)
{
  const int row = blockIdx.x * 4 + (threadIdx.x >> 6);
  const int lane = threadIdx.x & 63;
  const long long base = (long long)row * 1024;
  const float e0 = err[row * 2 + 0];
  const float e1 = err[row * 2 + 1];
  const float4* pz = (const float4*)(zinit + base);
  const ushort4* py = (const ushort4*)(Yc + base);
  const float4* pcb = (const float4*)ctrl_b;
  const float4* pw0 = (const float4*)err_W;
  const float4* pw1 = (const float4*)(err_W + 1024);
  const float4* peb = (const float4*)err_b;
  ushort4* pzb = (ushort4*)(zcb + base);
#pragma unroll
  for (int i = 0; i < 4; ++i) {
    int idx = lane + 64 * i;
    float4 zi = pz[idx]; ushort4 yu = py[idx];
    float4 cb = pcb[idx], w0 = pw0[idx], w1 = pw1[idx], eb = peb[idx];
    pzb[idx] = make_ushort4(
        f2bf(zi.x + bf2f(yu.x) + cb.x + e0 * w0.x + e1 * w1.x + eb.x + zi.x),
        f2bf(zi.y + bf2f(yu.y) + cb.y + e0 * w0.y + e1 * w1.y + eb.y + zi.y),
        f2bf(zi.z + bf2f(yu.z) + cb.z + e0 * w0.z + e1 * w1.z + eb.z + zi.z),
        f2bf(zi.w + bf2f(yu.w) + cb.w + e0 * w0.w + e1 * w1.w + eb.w + zi.w));
  }
}

// out[c][r] = bf16(in[r][c]);  in: [R][C] fp32. block (32,8), grid (C/32, R/32)
__global__ void transpose_cvt(const float* __restrict__ in, u16* __restrict__ out,
                              int R, int C)
{
  __shared__ float tile[32][33];
  const int x = blockIdx.x * 32 + threadIdx.x;
  const int y0 = blockIdx.y * 32;
#pragma unroll
  for (int i = 0; i < 32; i += 8)
    tile[threadIdx.y + i][threadIdx.x] = in[(long long)(y0 + threadIdx.y + i) * C + x];
  __syncthreads();
  const int ox = y0 + threadIdx.x;
  const int oy0 = blockIdx.x * 32;
#pragma unroll
  for (int i = 0; i < 32; i += 8)
    out[(long long)(oy0 + threadIdx.y + i) * R + ox] = f2bf(tile[threadIdx.x][threadIdx.y + i]);
}

__global__ void cvt_bf16(const float* __restrict__ in, u16* __restrict__ out, int n4)
{
  int i = blockIdx.x * 256 + threadIdx.x;
  if (i < n4) {
    float4 v = ((const float4*)in)[i];
    ((ushort4*)out)[i] = make_ushort4(f2bf(v.x), f2bf(v.y), f2bf(v.z), f2bf(v.w));
  }
}

// bvo[e] = sum_k bv[k] * Wo[k][e] + bo[e]  (E=1024); 64 cols/block, k split 4-way
__global__ void bias_fold(const float* __restrict__ bv, const float* __restrict__ Wo,
                          const float* __restrict__ bo, float* __restrict__ bvo)
{
  __shared__ float red[256];
  const int el = threadIdx.x & 63;
  const int e = blockIdx.x * 64 + el;
  const int q = threadIdx.x >> 6;
  float s = 0.f;
  for (int k = q * 256; k < q * 256 + 256; ++k) s += bv[k] * Wo[k * 1024 + e];
  red[threadIdx.x] = s;
  __syncthreads();
  if (q == 0) bvo[e] = red[el] + red[64 + el] + red[128 + el] + red[192 + el] + bo[e];
}

extern "C" void kernel_launch(void* const* d_in, const int* in_sizes, int n_in,
                              void* d_out, int out_size, void* d_ws, size_t ws_size,
                              hipStream_t stream)
{
  const float* z_init = (const float*)d_in[0];
  const float* ctrl   = (const float*)d_in[1];
  const float* err    = (const float*)d_in[2];
  const float* ctrl_W = (const float*)d_in[3];
  const float* ctrl_b = (const float*)d_in[4];
  const float* err_W  = (const float*)d_in[5];
  const float* err_b  = (const float*)d_in[6];
  // d_in[7]=Wq, d_in[8]=Wk, d_in[11]=bq, d_in[12]=bk: dead (softmax over 1 key == 1)
  const float* Wv    = (const float*)d_in[9];
  const float* Wo    = (const float*)d_in[10];
  const float* bv    = (const float*)d_in[13];
  const float* bo    = (const float*)d_in[14];
  const float* ln1_g = (const float*)d_in[15];
  const float* ln1_b = (const float*)d_in[16];
  const float* W1    = (const float*)d_in[17];
  const float* b1    = (const float*)d_in[18];
  const float* W2    = (const float*)d_in[19];
  const float* b2    = (const float*)d_in[20];
  const float* ln2_g = (const float*)d_in[21];
  const float* ln2_b = (const float*)d_in[22];

  constexpr int B = 8192, E = 1024, H = 4096;

  char* p = (char*)d_ws;
  auto alloc = [&](size_t bytes) {
    char* r = p;
    p += (bytes + 255) & ~(size_t)255;
    return r;
  };
  u16*   tmp_b  = (u16*)alloc((size_t)2 * B * E * 2); // Yc/Y/F0 + F1 (contiguous pair)
  u16*   tmp2_b = tmp_b + (size_t)B * E;              // split-K partial #2
  u16*   zc_b   = (u16*)alloc((size_t)B * E * 2);
  u16*   z1_b   = (u16*)alloc((size_t)B * E * 2);
  u16*   h_b    = (u16*)alloc((size_t)B * H * 2);
  u16*   ctrl16 = (u16*)alloc((size_t)B * 256 * 2);
  u16*   ctrlWT = (u16*)alloc((size_t)E * 256 * 2);
  u16*   Wv16   = (u16*)alloc((size_t)2 * E * E * 2);
  u16*   WoT    = (u16*)alloc((size_t)2 * E * E * 2);
  u16*   WvoT   = (u16*)alloc((size_t)2 * E * E * 2);
  u16*   W1T    = (u16*)alloc((size_t)2 * E * H * 2);
  u16*   W2T    = (u16*)alloc((size_t)2 * E * H * 2);
  float* bvo    = (float*)alloc((size_t)2 * E * 4);

  dim3 blk256(256);
  dim3 blk512(512);
  dim3 blkT(32, 8);

  // ---- per-launch weight prep (same work every call) ----
  cvt_bf16<<<(B * 256 / 4 + 255) / 256, blk256, 0, stream>>>(ctrl, ctrl16, B * 256 / 4);
  transpose_cvt<<<dim3(E / 32, 256 / 32), blkT, 0, stream>>>(ctrl_W, ctrlWT, 256, E);
  for (int i = 0; i < 2; ++i) {
    cvt_bf16<<<(E * E / 4 + 255) / 256, blk256, 0, stream>>>(Wv + (size_t)i * E * E, Wv16 + (size_t)i * E * E, E * E / 4);
    transpose_cvt<<<dim3(E / 32, E / 32), blkT, 0, stream>>>(Wo + (size_t)i * E * E, WoT + (size_t)i * E * E, E, E);
    transpose_cvt<<<dim3(H / 32, E / 32), blkT, 0, stream>>>(W1 + (size_t)i * E * H, W1T + (size_t)i * E * H, E, H);
    transpose_cvt<<<dim3(E / 32, H / 32), blkT, 0, stream>>>(W2 + (size_t)i * E * H, W2T + (size_t)i * E * H, H, E);
    bias_fold<<<E / 64, blk256, 0, stream>>>(bv + i * E, Wo + (size_t)i * E * E, bo + i * E, bvo + i * E);
  }
  // WvoT = Wo^T @ Wv^T  (A = WoT, Bt = Wv natural layout), bf16 out
  for (int i = 0; i < 2; ++i)
    gemm_bt<2, E, E><<<dim3(E / 128, E / 128), blk256, 0, stream>>>(
        WoT + (size_t)i * E * E, Wv16 + (size_t)i * E * E,
        nullptr, WvoT + (size_t)i * E * E, nullptr);

  // ---- prologue: z = z_init + ctrl@ctrl_W + ctrl_b + err@err_W + err_b ----
  gemm_bt<2, E, 256><<<dim3(B / 128, E / 128), blk256, 0, stream>>>(
      ctrl16, ctrlWT, nullptr, tmp_b, nullptr);
  prologue_fin<<<B / 4, blk256, 0, stream>>>(z_init, tmp_b, ctrl_b, err, err_W, err_b, zc_b);

  // ---- 3 cycles x 2 blocks ----
  for (int it = 0; it < 6; ++it) {
    int i = it & 1;
    int last = (it == 5);
    // attn_out (pre-bias): Y = zc @ Wvo  (bf16 out; bvo added in ln1)
    gemm_bt<2, E, E><<<dim3(B / 128, E / 128), blk256, 0, stream>>>(
        zc_b, WvoT + (size_t)i * E * E, nullptr, tmp_b, nullptr);
    ln1_kernel<<<B / 4, blk256, 0, stream>>>(zc_b, tmp_b, bvo + i * E,
        ln1_g + (size_t)i * E, ln1_b + (size_t)i * E, z1_b);
    // h = silu(z1 @ W1 + b1), bf16 — 256^2 8-phase, grid 32*16 = 512 wgs
    gemm256<1, 1, H / 256, E><<<dim3((B / 256) * (H / 256)), blk512, 0, stream>>>(
        z1_b, W1T + (size_t)i * E * H, h_b, b1 + (size_t)i * H);
    // F = h @ W2 (split-K=2, bf16 partials F0/F1; b2 added in ln2) — 256 wgs
    gemm256<2, 2, E / 256, H / 2><<<dim3((B / 256) * (E / 256) * 2), blk512, 0, stream>>>(
        h_b, W2T + (size_t)i * E * H, tmp_b, nullptr);
    ln2_kernel<<<B / 4, blk256, 0, stream>>>(z1_b, tmp_b, tmp2_b, b2 + (size_t)i * E,
        ln2_g + (size_t)i * E, ln2_b + (size_t)i * E, z_init,
        last ? (float*)d_out : nullptr, zc_b, last ? 0 : 1);
  }
}